// Round 1
// baseline (179.333 us; speedup 1.0000x reference)
//
#include <hip/hip_runtime.h>
#include <hip/hip_bf16.h>
#include <stdint.h>

#define NB 64
#define NA 33600
#define NK 500
#define HW3 25600
#define HW4 6400
#define HW5 1600
#define OFF4 25600
#define OFF5 32000

typedef unsigned int u32;
typedef unsigned long long u64;

__device__ __forceinline__ float sigf(float x) { return 1.0f / (1.0f + expf(-x)); }

__device__ __forceinline__ u32 f2key(float f) {
  u32 u = __float_as_uint(f);
  return (u & 0x80000000u) ? ~u : (u | 0x80000000u);
}
__device__ __forceinline__ float key2f(u32 k) {
  u32 u = (k & 0x80000000u) ? (k ^ 0x80000000u) : ~k;
  return __uint_as_float(u);
}

// ---------------- K1: masked max-score -> monotonic sort key -----------------
__global__ __launch_bounds__(256) void k_score(
    const float* __restrict__ cls3, const float* __restrict__ obj3,
    const float* __restrict__ cls4, const float* __restrict__ obj4,
    const float* __restrict__ cls5, const float* __restrict__ obj5,
    u32* __restrict__ keys)
{
  int t = blockIdx.x * 256 + threadIdx.x;
  if (t >= NB * NA) return;
  int b = t / NA;
  int a = t - b * NA;
  const float* cls; const float* obj; int pos, HW;
  if (a < OFF4)      { cls = cls3; obj = obj3; pos = a;        HW = HW3; }
  else if (a < OFF5) { cls = cls4; obj = obj4; pos = a - OFF4; HW = HW4; }
  else               { cls = cls5; obj = obj5; pos = a - OFF5; HW = HW5; }
  float so = sigf(obj[b * HW + pos]);
  float s0 = so * sigf(cls[(b * 2) * HW + pos]);
  float s1 = so * sigf(cls[(b * 2 + 1) * HW + pos]);
  float s  = fmaxf(s0, s1);
  float masked = (s > 0.3f) ? s : -1.0f;
  keys[t] = f2key(masked);
}

// ---------------- K2: per-batch exact top-500 via 48-bit radix select --------
// combined key = (u32 score key << 16) | (0xFFFF - anchor_idx)  -> all distinct,
// descending order == jax.lax.top_k order (value desc, index asc on ties).
__global__ __launch_bounds__(1024) void k_select(
    const u32* __restrict__ keys,
    int* __restrict__ top_idx, float* __restrict__ top_score)
{
  int b = blockIdx.x;
  int tid = threadIdx.x;
  __shared__ u32 hist[256];
  __shared__ u32 suf[256];
  __shared__ u64 coll[512];
  __shared__ u32 sh_R;
  __shared__ int sh_digit;
  __shared__ u32 sh_cnt;
  const u32* kb = keys + (size_t)b * NA;
  if (tid == 0) sh_cnt = 0;

  u64 prefix = 0, prefmask = 0;
  u32 R = NK;
  for (int pass = 0; pass < 6; ++pass) {
    int shift = 40 - 8 * pass;
    if (tid < 256) hist[tid] = 0;
    __syncthreads();
    for (int i = tid; i < NA; i += 1024) {
      u64 k48 = ((u64)kb[i] << 16) | (u32)(0xFFFF - i);
      if ((k48 & prefmask) == prefix)
        atomicAdd(&hist[(u32)(k48 >> shift) & 255u], 1u);
    }
    __syncthreads();
    if (tid < 256) suf[tid] = hist[tid];
    __syncthreads();
    for (int off = 1; off < 256; off <<= 1) {
      u32 add = 0;
      if (tid < 256 && tid + off < 256) add = suf[tid + off];
      __syncthreads();
      if (tid < 256) suf[tid] += add;
      __syncthreads();
    }
    if (tid < 256) {
      u32 s = suf[tid];
      u32 snext = (tid == 255) ? 0u : suf[tid + 1];
      if (s >= R && snext < R) { sh_digit = tid; sh_R = R - snext; }
    }
    __syncthreads();
    int dsel = sh_digit;
    R = sh_R;
    prefix |= ((u64)dsel) << shift;
    prefmask |= 0xFFull << shift;
    __syncthreads();
  }

  // collect all keys >= threshold (exactly 500, keys distinct)
  for (int i = tid; i < NA; i += 1024) {
    u64 k48 = ((u64)kb[i] << 16) | (u32)(0xFFFF - i);
    if (k48 >= prefix) {
      u32 slot = atomicAdd(&sh_cnt, 1u);
      if (slot < 512) coll[slot] = k48;
    }
  }
  __syncthreads();
  int n = (sh_cnt < (u32)NK) ? (int)sh_cnt : NK;
  // safety default fill (only matters if invariant ever broke)
  if (tid < NK) { top_idx[b * NK + tid] = 0; top_score[b * NK + tid] = -1.0f; }
  __syncthreads();
  // rank by counting (distinct keys -> unique ranks), write sorted
  for (int t = tid; t < n; t += 1024) {
    u64 k = coll[t];
    int rank = 0;
    for (int j = 0; j < n; ++j) rank += (coll[j] > k) ? 1 : 0;
    int idx = 0xFFFF - (int)(k & 0xFFFFull);
    top_idx[b * NK + rank] = idx;
    top_score[b * NK + rank] = key2f((u32)(k >> 16));
  }
}

// ---------------- K3: decode boxes + labels for selected anchors -------------
__global__ __launch_bounds__(256) void k_decode(
    const int* __restrict__ top_idx,
    const float* __restrict__ cls3, const float* __restrict__ obj3, const float* __restrict__ reg3,
    const float* __restrict__ cls4, const float* __restrict__ obj4, const float* __restrict__ reg4,
    const float* __restrict__ cls5, const float* __restrict__ obj5, const float* __restrict__ reg5,
    float4* __restrict__ boxes, float4* __restrict__ boxesoff,
    float* __restrict__ out_labels)
{
  int t = blockIdx.x * 256 + threadIdx.x;
  if (t >= NB * NK) return;
  int b = t / NK;
  int a = top_idx[t];
  const float *cls, *obj, *reg; int pos, HW, x, y; float stride;
  if (a < OFF4) {
    cls = cls3; obj = obj3; reg = reg3; pos = a; HW = HW3; stride = 8.0f;
    y = pos / 160; x = pos - y * 160;
  } else if (a < OFF5) {
    cls = cls4; obj = obj4; reg = reg4; pos = a - OFF4; HW = HW4; stride = 16.0f;
    y = pos / 80; x = pos - y * 80;
  } else {
    cls = cls5; obj = obj5; reg = reg5; pos = a - OFF5; HW = HW5; stride = 32.0f;
    y = pos / 40; x = pos - y * 40;
  }
  float dx = reg[(b * 4 + 0) * HW + pos];
  float dy = reg[(b * 4 + 1) * HW + pos];
  float dw = reg[(b * 4 + 2) * HW + pos];
  float dh = reg[(b * 4 + 3) * HW + pos];
  float cx = ((float)x + sigf(dx)) * stride;
  float cy = ((float)y + sigf(dy)) * stride;
  float w = expf(dw) * stride;
  float h = expf(dh) * stride;
  float x1 = cx - w * 0.5f, y1 = cy - h * 0.5f;
  float x2 = cx + w * 0.5f, y2 = cy + h * 0.5f;
  // label: exact argmax over per-class scores (tie -> class 0, like jnp.argmax)
  float so = sigf(obj[b * HW + pos]);
  float s0 = so * sigf(cls[(b * 2) * HW + pos]);
  float s1 = so * sigf(cls[(b * 2 + 1) * HW + pos]);
  int label = (s1 > s0) ? 1 : 0;
  float off = (float)label * 10000.0f;
  boxes[t]    = make_float4(x1, y1, x2, y2);
  boxesoff[t] = make_float4(x1 + off, y1 + off, x2 + off, y2 + off);
  out_labels[t] = (float)label;
}

// ---------------- K4: suppression bit-matrix (iou >= 0.5) --------------------
__global__ __launch_bounds__(256) void k_iou(
    const float4* __restrict__ boxesoff, u64* __restrict__ mask)
{
  int t = blockIdx.x * 256 + threadIdx.x;
  if (t >= NB * NK * 8) return;
  int w = t & 7;
  int bi = t >> 3;            // b*500 + i
  int b = bi / NK;
  float4 A = boxesoff[bi];
  float areaA = (A.z - A.x) * (A.w - A.y);
  const float4* base = boxesoff + b * NK;
  int j0 = w * 64;
  int jmax = (NK - j0 < 64) ? (NK - j0) : 64;
  u64 bits = 0;
  for (int jj = 0; jj < jmax; ++jj) {
    float4 Bx = base[j0 + jj];
    float areaB = (Bx.z - Bx.x) * (Bx.w - Bx.y);
    float ix1 = fmaxf(A.x, Bx.x);
    float iy1 = fmaxf(A.y, Bx.y);
    float ix2 = fminf(A.z, Bx.z);
    float iy2 = fminf(A.w, Bx.w);
    float iw = fmaxf(ix2 - ix1, 0.0f);
    float ih = fmaxf(iy2 - iy1, 0.0f);
    float inter = iw * ih;
    float uni = areaA + areaB - inter;
    float iou = inter / (uni + 1e-7f);
    bits |= ((u64)(iou >= 0.5f)) << jj;
  }
  mask[t] = bits;
}

// ---------------- K5: sequential greedy NMS scan + finalize ------------------
__global__ __launch_bounds__(64) void k_nms(
    const u64* __restrict__ mask, const float* __restrict__ top_score,
    const float4* __restrict__ boxes,
    float* __restrict__ out_boxes, float* __restrict__ out_scores,
    float* __restrict__ out_keep)
{
  __shared__ __align__(16) u64 m[504 * 8];
  int b = blockIdx.x;
  int lane = threadIdx.x;
  const u64* mb = mask + (size_t)b * (NK * 8);
  for (int i = lane; i < NK * 8; i += 64) m[i] = mb[i];
  if (lane < 32) m[NK * 8 + lane] = 0;   // pad rows 500..503

  u64 validw[8];
#pragma unroll
  for (int c = 0; c < 8; ++c) {
    int r = c * 64 + lane;
    float s = (r < NK) ? top_score[b * NK + r] : -1.0f;
    validw[c] = __ballot(s > 0.3f);
  }
  __syncthreads();

  const ulonglong2* m2 = reinterpret_cast<const ulonglong2*>(m);
  u64 supp[8] = {0, 0, 0, 0, 0, 0, 0, 0};
  u64 kw[8]   = {0, 0, 0, 0, 0, 0, 0, 0};

#pragma unroll
  for (int w = 0; w < 8; ++w) {
    const int WP2 = (w & ~1) >> 1;          // first pair still needed
    const int IMAX = (w == 7) ? 52 : 64;
    ulonglong2 A[4], Bv[4];
#pragma unroll
    for (int p = 0; p < 4; ++p) A[p] = m2[(w * 64 + 0) * 4 + p];
#pragma unroll
    for (int p = 0; p < 4; ++p) Bv[p] = m2[(w * 64 + 1) * 4 + p];
    u64 vw = validw[w];
    for (int ib = 0; ib < IMAX; ib += 2) {
      int i = w * 64 + ib;
      {
        ulonglong2 S[4];
#pragma unroll
        for (int p = 0; p < 4; ++p) S[p] = A[p];
#pragma unroll
        for (int p = 0; p < 4; ++p) if (p >= WP2) A[p] = m2[(i + 2) * 4 + p];
        bool kp = (((vw >> ib) & 1ull) != 0) && (((supp[w] >> ib) & 1ull) == 0);
        if (kp) {
          kw[w] |= (1ull << ib);
#pragma unroll
          for (int p = 0; p < 4; ++p) if (p >= WP2) {
            supp[2 * p]     |= S[p].x;
            supp[2 * p + 1] |= S[p].y;
          }
        }
      }
      {
        int ib1 = ib + 1;
        ulonglong2 S[4];
#pragma unroll
        for (int p = 0; p < 4; ++p) S[p] = Bv[p];
#pragma unroll
        for (int p = 0; p < 4; ++p) if (p >= WP2) Bv[p] = m2[(i + 3) * 4 + p];
        bool kp = (((vw >> ib1) & 1ull) != 0) && (((supp[w] >> ib1) & 1ull) == 0);
        if (kp) {
          kw[w] |= (1ull << ib1);
#pragma unroll
          for (int p = 0; p < 4; ++p) if (p >= WP2) {
            supp[2 * p]     |= S[p].x;
            supp[2 * p + 1] |= S[p].y;
          }
        }
      }
    }
  }

#pragma unroll
  for (int c = 0; c < 8; ++c) {
    int r = c * 64 + lane;
    if (r < NK) {
      int kp = (int)((kw[c] >> lane) & 1ull);
      float4 bx = boxes[b * NK + r];
      float s = top_score[b * NK + r];
      float4 ob;
      ob.x = kp ? bx.x : 0.0f;
      ob.y = kp ? bx.y : 0.0f;
      ob.z = kp ? bx.z : 0.0f;
      ob.w = kp ? bx.w : 0.0f;
      reinterpret_cast<float4*>(out_boxes)[b * NK + r] = ob;
      out_scores[b * NK + r] = kp ? s : 0.0f;
      out_keep[b * NK + r]   = kp ? 1.0f : 0.0f;
    }
  }
}

// ---------------- launcher ---------------------------------------------------
extern "C" void kernel_launch(void* const* d_in, const int* in_sizes, int n_in,
                              void* d_out, int out_size, void* d_ws, size_t ws_size,
                              hipStream_t stream) {
  const float* cls3 = (const float*)d_in[0];
  const float* reg3 = (const float*)d_in[1];
  const float* obj3 = (const float*)d_in[2];
  const float* cls4 = (const float*)d_in[3];
  const float* reg4 = (const float*)d_in[4];
  const float* obj4 = (const float*)d_in[5];
  const float* cls5 = (const float*)d_in[6];
  const float* reg5 = (const float*)d_in[7];
  const float* obj5 = (const float*)d_in[8];

  char* ws = (char*)d_ws;
  u32*    keys      = (u32*)   (ws + 0);         //  8,601,600 B
  int*    top_idx   = (int*)   (ws + 8601600);   //    128,000 B
  float*  top_score = (float*) (ws + 8729600);   //    128,000 B
  float4* boxes     = (float4*)(ws + 8857600);   //    512,000 B
  float4* boxesoff  = (float4*)(ws + 9369600);   //    512,000 B
  u64*    mask      = (u64*)   (ws + 9881600);   //  2,048,000 B  (total ~11.4 MB)

  float* out        = (float*)d_out;
  float* out_boxes  = out;            // 128000
  float* out_scores = out + 128000;   //  32000
  float* out_labels = out + 160000;   //  32000
  float* out_keep   = out + 192000;   //  32000

  k_score<<<(NB * NA + 255) / 256, 256, 0, stream>>>(cls3, obj3, cls4, obj4, cls5, obj5, keys);
  k_select<<<NB, 1024, 0, stream>>>(keys, top_idx, top_score);
  k_decode<<<(NB * NK + 255) / 256, 256, 0, stream>>>(top_idx,
      cls3, obj3, reg3, cls4, obj4, reg4, cls5, obj5, reg5,
      boxes, boxesoff, out_labels);
  k_iou<<<(NB * NK * 8 + 255) / 256, 256, 0, stream>>>(boxesoff, mask);
  k_nms<<<NB, 64, 0, stream>>>(mask, top_score, boxes, out_boxes, out_scores, out_keep);
}